// Round 5
// baseline (172.196 us; speedup 1.0000x reference)
//
#include <hip/hip_runtime.h>

#define FD 32          // feature dim
#define RPB 8          // rows per block
#define CPT 2          // cols per thread -> block covers 512 cols
#define BLK 256        // threads per block

// packed dual-fp32 add (B pre-negated in registers => computes a-b for 2 d's)
__device__ __forceinline__ float2 pk_add(float2 a, float2 b) {
    float2 r;
    asm("v_pk_add_f32 %0, %1, %2" : "=v"(r) : "v"(a), "v"(b));
    return r;
}
// acc = max(acc, |x|, |y|) in ONE VALU inst (abs = free VOP3 input modifier)
__device__ __forceinline__ float max3abs(float a, float x, float y) {
    float r;
    asm("v_max3_f32 %0, %1, abs(%2), abs(%3)" : "=v"(r) : "v"(a), "v"(x), "v"(y));
    return r;
}

// (256, 8): request 8 waves/EU resident -> compiler caps VGPR at 64.
__global__ __launch_bounds__(256, 8) void cheb_kernel(
    const float* __restrict__ A, const float* __restrict__ B,
    float* __restrict__ C, int M)
{
    const int tid = threadIdx.x;
    const int c0  = blockIdx.x * (BLK * CPT) + tid * CPT;  // 2 output cols
    const int r0  = blockIdx.y * RPB;

    // ---- This thread's 2 B columns, negated, in 32 VGPRs (fits 8 waves/SIMD).
    float2 nb0[FD / 2], nb1[FD / 2];
    {
        const float* brow = B + (size_t)c0 * FD;
#pragma unroll
        for (int q = 0; q < 8; ++q) {
            const float4 v = *reinterpret_cast<const float4*>(brow + q * 4);
            nb0[2 * q + 0] = make_float2(-v.x, -v.y);
            nb0[2 * q + 1] = make_float2(-v.z, -v.w);
            const float4 w = *reinterpret_cast<const float4*>(brow + FD + q * 4);
            nb1[2 * q + 0] = make_float2(-w.x, -w.y);
            nb1[2 * q + 1] = make_float2(-w.z, -w.w);
        }
    }

    // ---- Stream A rows (wave-uniform, L1-resident; 32 waves/CU hide the latency).
#pragma unroll 2
    for (int r = 0; r < RPB; ++r) {
        const float* arow = A + (size_t)(r0 + r) * FD;
        float acc0 = 0.0f, acc1 = 0.0f;   // distances >= 0
#pragma unroll
        for (int q = 0; q < 8; ++q) {
            const float4 av = *reinterpret_cast<const float4*>(arow + q * 4);
            const float2 a01 = make_float2(av.x, av.y);
            const float2 a23 = make_float2(av.z, av.w);
            float2 d;
            d = pk_add(a01, nb0[2 * q + 0]); acc0 = max3abs(acc0, d.x, d.y);
            d = pk_add(a23, nb0[2 * q + 1]); acc0 = max3abs(acc0, d.x, d.y);
            d = pk_add(a01, nb1[2 * q + 0]); acc1 = max3abs(acc1, d.x, d.y);
            d = pk_add(a23, nb1[2 * q + 1]); acc1 = max3abs(acc1, d.x, d.y);
        }
        // coalesced: wave writes 512B contiguous
        *reinterpret_cast<float2*>(C + (size_t)(r0 + r) * M + c0) = make_float2(acc0, acc1);
    }
}

extern "C" void kernel_launch(void* const* d_in, const int* in_sizes, int n_in,
                              void* d_out, int out_size, void* d_ws, size_t ws_size,
                              hipStream_t stream) {
    const float* A = (const float*)d_in[0];
    const float* B = (const float*)d_in[1];
    float* C = (float*)d_out;
    const int N = in_sizes[0] / FD;   // 4096
    const int M = in_sizes[1] / FD;   // 4096
    dim3 grid(M / (BLK * CPT), N / RPB);   // 8 x 512 = 4096 blocks = 16/CU
    cheb_kernel<<<grid, BLK, 0, stream>>>(A, B, C, M);
}

// Round 6
// 33.919 us; speedup vs baseline: 5.0767x; 5.0767x over previous
//
#include <hip/hip_runtime.h>

#define FD 32          // feature dim
#define RPB 16         // rows per block
#define CPT 2          // cols per thread -> block covers 512 cols
#define BLK 256        // threads per block

typedef float f32x16 __attribute__((ext_vector_type(16)));

// Scalar-pipe broadcast load of one A row (128B) into 32 SGPRs.
__device__ __forceinline__ void sload_row(const float* p, f32x16& lo, f32x16& hi) {
    asm volatile("s_load_dwordx16 %0, %2, 0x0\n\t"
                 "s_load_dwordx16 %1, %2, 0x40"
                 : "=&s"(lo), "=&s"(hi) : "s"(p));
}
// Wait for outstanding scalar loads; "+s" operands create the data dep so
// consumers cannot be hoisted above the wait (rule #18).
__device__ __forceinline__ void swait(f32x16& lo, f32x16& hi) {
    asm volatile("s_waitcnt lgkmcnt(0)" : "+s"(lo), "+s"(hi));
}
// a - b for two d's in ONE inst: vb holds (-b0,-b1) in VGPRs, sa is the
// wave-uniform A pair in SGPRs (VOP3P allows one scalar source).
__device__ __forceinline__ float2 pk_add_vs(float2 vb, float2 sa) {
    float2 r;
    asm("v_pk_add_f32 %0, %1, %2" : "=v"(r) : "v"(vb), "s"(sa));
    return r;
}
// acc = max(acc, |x|, |y|) in ONE inst (abs = free VOP3 input modifier).
__device__ __forceinline__ float max3abs(float a, float x, float y) {
    float r;
    asm("v_max3_f32 %0, %1, abs(%2), abs(%3)" : "=v"(r) : "v"(a), "v"(x), "v"(y));
    return r;
}

__device__ __forceinline__ void row_compute(const f32x16& lo, const f32x16& hi,
                                            const float2* nb0, const float2* nb1,
                                            float* cptr) {
    float acc0 = 0.0f, acc1 = 0.0f;   // distances >= 0
#pragma unroll
    for (int p = 0; p < 8; ++p) {
        const float2 sa = make_float2(lo[2 * p], lo[2 * p + 1]);
        const float2 d0 = pk_add_vs(nb0[p], sa); acc0 = max3abs(acc0, d0.x, d0.y);
        const float2 d1 = pk_add_vs(nb1[p], sa); acc1 = max3abs(acc1, d1.x, d1.y);
    }
#pragma unroll
    for (int p = 0; p < 8; ++p) {
        const float2 sa = make_float2(hi[2 * p], hi[2 * p + 1]);
        const float2 d0 = pk_add_vs(nb0[8 + p], sa); acc0 = max3abs(acc0, d0.x, d0.y);
        const float2 d1 = pk_add_vs(nb1[8 + p], sa); acc1 = max3abs(acc1, d1.x, d1.y);
    }
    *reinterpret_cast<float2*>(cptr) = make_float2(acc0, acc1);  // wave: 512B contiguous
}

__global__ __launch_bounds__(256) void cheb_kernel(
    const float* __restrict__ A, const float* __restrict__ B,
    float* __restrict__ C, int M)
{
    const int tid = threadIdx.x;
    const int c0  = blockIdx.x * (BLK * CPT) + tid * CPT;  // this thread's 2 cols
    const int r0  = blockIdx.y * RPB;

    // ---- This thread's 2 B columns, negated, in 32 VGPRs (static indexing only).
    float2 nb0[FD / 2], nb1[FD / 2];
    {
        const float* brow = B + (size_t)c0 * FD;
#pragma unroll
        for (int q = 0; q < 8; ++q) {
            const float4 v = *reinterpret_cast<const float4*>(brow + q * 4);
            nb0[2 * q + 0] = make_float2(-v.x, -v.y);
            nb0[2 * q + 1] = make_float2(-v.z, -v.w);
            const float4 w = *reinterpret_cast<const float4*>(brow + FD + q * 4);
            nb1[2 * q + 0] = make_float2(-w.x, -w.y);
            nb1[2 * q + 1] = make_float2(-w.z, -w.w);
        }
    }

    // ---- A rows stream through the SCALAR pipe (SGPR broadcast), 2-row ping-pong.
    const float* arow = A + (size_t)r0 * FD;
    float* crow = C + (size_t)r0 * M + c0;

    f32x16 lo0, hi0, lo1, hi1;
    sload_row(arow,      lo0, hi0);
    sload_row(arow + FD, lo1, hi1);

#pragma unroll 2
    for (int rr = 0; rr < RPB; rr += 2) {
        swait(lo0, hi0);
        row_compute(lo0, hi0, nb0, nb1, crow);
        if (rr + 2 < RPB) sload_row(arow + (size_t)(rr + 2) * FD, lo0, hi0);
        crow += M;

        swait(lo1, hi1);
        row_compute(lo1, hi1, nb0, nb1, crow);
        if (rr + 3 < RPB) sload_row(arow + (size_t)(rr + 3) * FD, lo1, hi1);
        crow += M;
    }
}

extern "C" void kernel_launch(void* const* d_in, const int* in_sizes, int n_in,
                              void* d_out, int out_size, void* d_ws, size_t ws_size,
                              hipStream_t stream) {
    const float* A = (const float*)d_in[0];
    const float* B = (const float*)d_in[1];
    float* C = (float*)d_out;
    const int N = in_sizes[0] / FD;   // 4096
    const int M = in_sizes[1] / FD;   // 4096
    dim3 grid(M / (BLK * CPT), N / RPB);   // 8 x 256 = 2048 blocks = 8/CU
    cheb_kernel<<<grid, BLK, 0, stream>>>(A, B, C, M);
}